// Round 16
// baseline (422.651 us; speedup 1.0000x reference)
//
#include <hip/hip_runtime.h>
#include <hip/hip_bf16.h>

// Problem dims (fixed by reference): D=512, B=32, S_c=256, S_q(T)=32
#define DIMD 512
#define NB   32
#define NS   256
#define NT   32
// LDS strides chosen for bank-conflict freedom (dword-stride ≡ 1/2 mod 32)
#define SA_STR  66    // ctxdm slice rows (bf16): 132B = 33 dw ≡ 1
#define SCT_STR 258   // ctxT slice rows (bf16): 516B = 129 dw ≡ 1
#define SR_STR  132   // r/qh chunks (fp32): q-groups on distinct banks

typedef __bf16 bf16x8 __attribute__((ext_vector_type(8)));
typedef float  f32x4  __attribute__((ext_vector_type(4)));
typedef unsigned long long u64;

__device__ __forceinline__ float tanh_fast(float x) {
    float e = __expf(2.f * x);
    return 1.f - 2.f / (e + 1.f);
}

// async global->LDS, 16B per lane; lds dest = wave-uniform base + lane*16
__device__ __forceinline__ void gl_lds16(const __bf16* g, __bf16* l) {
    __builtin_amdgcn_global_load_lds((const __attribute__((address_space(1))) void*)g,
                                     (__attribute__((address_space(3))) void*)l, 16, 0, 0);
}

// ---- tagged-data sync: {value,tag} in one 64-bit relaxed atomic (proven r10-15).
// Tags 1..NT never collide with the 0xAAAAAAAA workspace poison.
__device__ __forceinline__ void pub64(u64* p, float v, unsigned tag) {
    u64 pk = ((u64)__float_as_uint(v) << 32) | (u64)tag;
    __hip_atomic_store(p, pk, __ATOMIC_RELAXED, __HIP_MEMORY_SCOPE_AGENT);
}
__device__ __forceinline__ float poll64(const u64* p, unsigned tag) {
    u64 v = __hip_atomic_load(p, __ATOMIC_RELAXED, __HIP_MEMORY_SCOPE_AGENT);
    while ((unsigned)v != tag) {
        __builtin_amdgcn_s_sleep(1);
        v = __hip_atomic_load(p, __ATOMIC_RELAXED, __HIP_MEMORY_SCOPE_AGENT);
    }
    return __uint_as_float((unsigned)(v >> 32));
}

// ---------------- fused prep: acat + q cast + EIGHT weight transposes ----------------
__global__ void k_prep_all(const float* __restrict__ ctxin, const float* __restrict__ img,
                           const float* __restrict__ qin,
                           const float* __restrict__ Wfc1, const float* __restrict__ Wfc2,
                           const float* __restrict__ Wdm, const float* __restrict__ Wqm,
                           const float* __restrict__ Wrm, const float* __restrict__ Wrr,
                           const float* __restrict__ Wrg, const float* __restrict__ Wqg,
                           __bf16* __restrict__ acat, __bf16* __restrict__ qp,
                           __bf16* __restrict__ wcatT, __bf16* __restrict__ wdmT,
                           __bf16* __restrict__ wqmT, __bf16* __restrict__ wrmT,
                           __bf16* __restrict__ wrrT, __bf16* __restrict__ wrgT,
                           __bf16* __restrict__ wqgT) {
    int row = blockIdx.x;
    if (row < 8192) {
        int b = row >> 8, s = row & 255;
        const float* c  = ctxin + ((size_t)s * NB + b) * DIMD;
        const float* im = img   + ((size_t)s * NB + b) * DIMD;
        __bf16* o = acat + (size_t)row * 1024;
        for (int d = threadIdx.x; d < DIMD; d += 256) {
            o[d]       = (__bf16)c[d];
            o[512 + d] = (__bf16)im[d];
        }
    } else if (row < 10240) {
        int idx = (row - 8192) * 256 + threadIdx.x;   // 2048*256 = NT*NB*DIMD
        qp[idx] = (__bf16)qin[idx];
    } else {
        __shared__ float tile[32][33];
        int zz = (row - 10240) >> 8;       // matrix id 0..7
        int idx = (row - 10240) & 255;
        int bx = idx & 15, by = idx >> 4;
        int x = threadIdx.x & 31, y = threadIdx.x >> 5;   // 32 x 8
        const float* src = (zz == 0) ? Wfc1 : (zz == 1) ? Wfc2 : (zz == 2) ? Wdm
                         : (zz == 3) ? Wqm : (zz == 4) ? Wrm : (zz == 5) ? Wrr
                         : (zz == 6) ? Wrg : Wqg;
        __bf16* dst; int stride, off;
        if (zz < 2) { dst = wcatT; stride = 1024; off = zz * 512; }
        else {
            dst = (zz == 2) ? wdmT : (zz == 3) ? wqmT : (zz == 4) ? wrmT
                : (zz == 5) ? wrrT : (zz == 6) ? wrgT : wqgT;
            stride = 512; off = 0;
        }
        int c0 = bx * 32, r0 = by * 32;
#pragma unroll
        for (int k = 0; k < 32; k += 8)
            tile[y + k][x] = src[(size_t)(r0 + y + k) * DIMD + c0 + x];
        __syncthreads();
#pragma unroll
        for (int k = 0; k < 32; k += 8)
            dst[(size_t)(c0 + y + k) * stride + off + r0 + x] = (__bf16)tile[x][y + k];
    }
}

// ---------------- 128x64-tile GEMM body, BK=64 (2 blocks/CU: barrier drain of
// one block overlaps the co-resident block's MFMA — proven r15) ----------------
__device__ __forceinline__ void gemm_tile(const __bf16* __restrict__ A,
                                          const __bf16* __restrict__ BT,
                                          const float* __restrict__ bias1,
                                          const float* __restrict__ bias2,
                                          void* __restrict__ out, int N, int K,
                                          int m0, int n0, int out_f32,
                                          __bf16* As, __bf16* Bs) {
    int tid = threadIdx.x, wave = tid >> 6, lane = tid & 63;
    int wm_ = wave >> 1, wn = wave & 1;
    int lr = lane & 15, lq = lane >> 4;
    int lrow = lane >> 3, lcol8 = (lane & 7) * 8;   // staging: 8 rows x 64 k per chunk

    f32x4 acc[4][2];
#pragma unroll
    for (int i = 0; i < 4; i++)
#pragma unroll
        for (int j = 0; j < 2; j++) acc[i][j] = (f32x4){0.f, 0.f, 0.f, 0.f};

    for (int kk = 0; kk < K; kk += 64) {
#pragma unroll
        for (int i = 0; i < 4; i++) {
            int g = wave * 4 + i;
            gl_lds16(A + (size_t)(m0 + g * 8 + lrow) * K + kk + lcol8, As + g * 512);
        }
#pragma unroll
        for (int i = 0; i < 2; i++) {
            int g = wave * 2 + i;
            gl_lds16(BT + (size_t)(n0 + g * 8 + lrow) * K + kk + lcol8, Bs + g * 512);
        }
        __syncthreads();
#pragma unroll
        for (int k2 = 0; k2 < 64; k2 += 32) {
            bf16x8 af[4], bfv[2];
#pragma unroll
            for (int i = 0; i < 4; i++)
                af[i] = *(const bf16x8*)(As + (wm_ * 64 + i * 16 + lr) * 64 + k2 + lq * 8);
#pragma unroll
            for (int j = 0; j < 2; j++)
                bfv[j] = *(const bf16x8*)(Bs + (wn * 32 + j * 16 + lr) * 64 + k2 + lq * 8);
#pragma unroll
            for (int i = 0; i < 4; i++)
#pragma unroll
                for (int j = 0; j < 2; j++)
                    acc[i][j] = __builtin_amdgcn_mfma_f32_16x16x32_bf16(af[i], bfv[j], acc[i][j], 0, 0, 0);
        }
        __syncthreads();
    }

#pragma unroll
    for (int i = 0; i < 4; i++)
#pragma unroll
        for (int j = 0; j < 2; j++) {
            int col = n0 + wn * 32 + j * 16 + lr;
            float bs = (bias1 ? bias1[col] : 0.f) + (bias2 ? bias2[col] : 0.f);
#pragma unroll
            for (int r = 0; r < 4; r++) {
                int row = m0 + wm_ * 64 + i * 16 + lq * 4 + r;   // verified C/D layout
                float v = acc[i][j][r] + bs;
                if (out_f32) ((float*)out)[(size_t)row * N + col] = v;
                else         ((__bf16*)out)[(size_t)row * N + col] = (__bf16)v;
            }
        }
}

// g1: ctx = acat @ W_cat^T + bfc1 + bfc2  (grid 64 x 8 = 512 blocks, 2/CU)
__global__ void k_gemm(const __bf16* __restrict__ A, const __bf16* __restrict__ BT,
                       const float* __restrict__ bias1, const float* __restrict__ bias2,
                       void* __restrict__ out, int M, int N, int K, int out_f32) {
    __shared__ __bf16 As[128 * 64];
    __shared__ __bf16 Bs[64 * 64];
    gemm_tile(A, BT, bias1, bias2, out, N, K, blockIdx.x * 128, blockIdx.y * 64, out_f32, As, Bs);
}

// fused post-g1 (round 16: ctxT transpose REMOVED — scan stages it directly
// from row-major ctxb): blocks 0..511 g2; 512..575 qm GEMM
__global__ void k_fused(const __bf16* __restrict__ ctxb, const __bf16* __restrict__ wdmT,
                        const float* __restrict__ bdm, __bf16* __restrict__ ctxdm,
                        const __bf16* __restrict__ qp, const __bf16* __restrict__ wqmT,
                        const float* __restrict__ bqm, float* __restrict__ qmf) {
    __shared__ __bf16 As[128 * 64];
    __shared__ __bf16 Bs[64 * 64];
    int bid = blockIdx.x;
    if (bid < 512) {
        gemm_tile(ctxb, wdmT, bdm, nullptr, ctxdm, 512, 512,
                  (bid & 63) * 128, (bid >> 6) * 64, 0, As, Bs);
    } else {
        int b2 = bid - 512;
        gemm_tile(qp, wqmT, bqm, nullptr, qmf, 512, 512,
                  (b2 & 7) * 128, (b2 >> 3) * 64, 1, As, Bs);
    }
}

// ---------------- scan: round-13 structure (best measured), in-LDS ctx transpose ----------------
// grid 256 = 32 batches x 8 e-slices; block 512 threads (8 waves), 1 block/CU.
// XCD-affinity: b = bid&31, j = bid>>5. Tagged-data sync, fused final step.
__global__ __launch_bounds__(512, 2) void k_scan(
    const __bf16* __restrict__ ctxdm,  // [b*256+s][512]
    const __bf16* __restrict__ ctxb,   // [b*256+s][512] (row-major ctx)
    const __bf16* __restrict__ wrmT,   // [c][d]
    const __bf16* __restrict__ wrrT,   // [c][d]
    const float* __restrict__ qmf,     // [t*32+b][512]
    const float* __restrict__ wms, const float* __restrict__ brm,
    const float* __restrict__ brr,
    const float* __restrict__ qh,      // [b][512]
    const __bf16* __restrict__ wrgT,   // [c][d]
    const __bf16* __restrict__ wqgT,   // [c][d]
    const float* __restrict__ brg, const float* __restrict__ bqg,
    u64* parts,                        // [b][8][256] tagged
    u64* rpub,                         // [b][512] tagged
    float* __restrict__ out) {         // [b][512] final g
    int bid = blockIdx.x;
    int b = bid & 31, j = bid >> 5;        // XCD-affinity mapping
    int tid = threadIdx.x, wave = tid >> 6, lane = tid & 63;
    int g = lane >> 3, i = lane & 7;       // s-subgroup, e-chunk

    __shared__ __bf16 sA[256 * SA_STR];    // 33.8 KB (ctxdm slice)
    __shared__ __bf16 sCT[64 * SCT_STR];   // 33.0 KB (ctx slice, transposed in-LDS)
    __shared__ float  sQ[NT * 64];         //  8 KB
    __shared__ float  sq[512];             // B1 gather sums
    __shared__ float  sp[256];             // exp values
    __shared__ float  s4[4];
    __shared__ float  sps[8 * 68];         // B1 per-wave partials (stride 68)
    __shared__ float  srm[64], sh[64];
    __shared__ float  sr4[4 * SR_STR];     // r in 4 padded chunks
    __shared__ float  sqh4[4 * SR_STR];    // qh in 4 padded chunks (final step)
    __shared__ float  smv[512];

    // ---- one-time staging ----
    for (int c = tid; c < 2048; c += 512) {            // sA: 256 rows x 64 e
        int row = c >> 3, c8 = c & 7;
        *(bf16x8*)(sA + row * SA_STR + c8 * 8) =
            *(const bf16x8*)(ctxdm + ((size_t)(b * NS + row)) * DIMD + j * 64 + c8 * 8);
    }
    for (int c = tid; c < 2048; c += 512) {            // sCT via in-LDS transpose:
        int row = c >> 3, c8 = c & 7;                  // vector-read 8 cols of row s,
        bf16x8 v = *(const bf16x8*)(ctxb + ((size_t)(b * NS + row)) * DIMD + j * 64 + c8 * 8);
#pragma unroll
        for (int u = 0; u < 8; u++)                    // scalar-scatter to [col][s]
            sCT[(c8 * 8 + u) * SCT_STR + row] = v[u];
    }
    for (int c = tid; c < NT * 64; c += 512) {         // sQ
        int tt = c >> 6, e = c & 63;
        sQ[c] = qmf[((size_t)tt * NB + b) * DIMD + j * 64 + e];
    }
    sqh4[(tid >> 7) * SR_STR + (tid & 127)] = qh[(size_t)b * DIMD + tid];
    // weight slice -> registers: thread (m,cl,q) owns d in [q*128,(q+1)*128)
    int m = tid >> 8, cl = (tid >> 2) & 63, q = tid & 3;
    const __bf16* wp = (m ? wrrT : wrmT) + ((size_t)(j * 64 + cl)) * DIMD + q * 128;
    bf16x8 wreg[16];
#pragma unroll
    for (int u = 0; u < 16; u++) wreg[u] = *(const bf16x8*)(wp + u * 8);

    float wm[8];
#pragma unroll
    for (int u = 0; u < 8; u++) wm[u] = wms[j * 64 + i * 8 + u];
    if (tid < 64) {
        srm[tid] = brm[j * 64 + tid];            // rm_0 slice (r0 = 0)
        sh[tid]  = tanh_fast(brr[j * 64 + tid]); // h_0 slice
    }
    __syncthreads();

    for (int t = 0; t < NT; t++) {
        unsigned tag = (unsigned)(t + 1);
        // ---- phase A: partial logits, published directly from the loop ----
        float rq[8];
#pragma unroll
        for (int u = 0; u < 8; u++) rq[u] = srm[i * 8 + u] + sQ[t * 64 + i * 8 + u];
#pragma unroll
        for (int k = 0; k < 4; k++) {
            int s = wave * 32 + k * 8 + g;
            bf16x8 cv = *(const bf16x8*)(sA + s * SA_STR + i * 8);
            float a = 0.f;
#pragma unroll
            for (int u = 0; u < 8; u++)
                a += tanh_fast((float)cv[u] + rq[u]) * wm[u];
            a += __shfl_xor(a, 1); a += __shfl_xor(a, 2); a += __shfl_xor(a, 4);
            if (i == 0) pub64(&parts[(b * 8 + j) * NS + s], a, tag);
        }

        // ---- phase B1: batched poll, softmax, weighted ctx sum -> r-slice ----
        {
            int s = tid >> 1, jh = (tid & 1) * 4;
            const u64* p0 = &parts[(b * 8 + jh + 0) * NS + s];
            const u64* p1 = &parts[(b * 8 + jh + 1) * NS + s];
            const u64* p2 = &parts[(b * 8 + jh + 2) * NS + s];
            const u64* p3 = &parts[(b * 8 + jh + 3) * NS + s];
            u64 v0, v1, v2, v3;
            for (;;) {
                v0 = __hip_atomic_load(p0, __ATOMIC_RELAXED, __HIP_MEMORY_SCOPE_AGENT);
                v1 = __hip_atomic_load(p1, __ATOMIC_RELAXED, __HIP_MEMORY_SCOPE_AGENT);
                v2 = __hip_atomic_load(p2, __ATOMIC_RELAXED, __HIP_MEMORY_SCOPE_AGENT);
                v3 = __hip_atomic_load(p3, __ATOMIC_RELAXED, __HIP_MEMORY_SCOPE_AGENT);
                if ((unsigned)v0 == tag && (unsigned)v1 == tag &&
                    (unsigned)v2 == tag && (unsigned)v3 == tag) break;
                __builtin_amdgcn_s_sleep(1);
            }
            sq[tid] = __uint_as_float((unsigned)(v0 >> 32)) + __uint_as_float((unsigned)(v1 >> 32))
                    + __uint_as_float((unsigned)(v2 >> 32)) + __uint_as_float((unsigned)(v3 >> 32));
        }
        __syncthreads();
        float ev = 0.f;
        if (tid < NS) { ev = __expf(sq[2 * tid] + sq[2 * tid + 1]); sp[tid] = ev; }
#pragma unroll
        for (int off = 32; off; off >>= 1) ev += __shfl_xor(ev, off);
        if (tid < NS && lane == 0) s4[wave] = ev;
        __syncthreads();
        float inv = 1.f / (s4[0] + s4[1] + s4[2] + s4[3]);
        {
            const __bf16* cp = sCT + lane * SCT_STR + wave * 32;
            const float* pp = sp + wave * 32;
            float a = 0.f;
#pragma unroll
            for (int k = 0; k < 32; k += 8) {
                bf16x8 v = *(const bf16x8*)(cp + k);
#pragma unroll
                for (int u = 0; u < 8; u++) a = fmaf(pp[k + u], (float)v[u], a);
            }
            sps[wave * 68 + lane] = a;
        }
        __syncthreads();
        if (tid < 64) {
            float a = 0.f;
#pragma unroll
            for (int w2 = 0; w2 < 8; w2++) a += sps[w2 * 68 + tid];
            float rv = a * inv + sh[tid];
            pub64(&rpub[b * DIMD + j * 64 + tid], rv, tag);
        }

        // ---- phase B2 / final: gather full r ----
        sr4[(tid >> 7) * SR_STR + (tid & 127)] = poll64(&rpub[b * DIMD + tid], tag);
        __syncthreads();
        if (t < NT - 1) {
            // register-weight matvec -> rm/h (block-local)
            const float* sv = sr4 + q * SR_STR;   // q-groups on distinct banks
            float a0 = 0.f, a1 = 0.f;
#pragma unroll
            for (int u = 0; u < 16; u += 2) {
                bf16x8 w0 = wreg[u], w1 = wreg[u + 1];
#pragma unroll
                for (int e = 0; e < 8; e++) {
                    a0 = fmaf(sv[u * 8 + e],     (float)w0[e], a0);
                    a1 = fmaf(sv[u * 8 + 8 + e], (float)w1[e], a1);
                }
            }
            smv[tid] = a0 + a1;
            __syncthreads();
            if (tid < 128) {
                int m2 = tid >> 6, cl3 = tid & 63;
                float a = smv[m2 * 256 + cl3 * 4] + smv[m2 * 256 + cl3 * 4 + 1]
                        + smv[m2 * 256 + cl3 * 4 + 2] + smv[m2 * 256 + cl3 * 4 + 3];
                int col = j * 64 + cl3;
                if (m2 == 0) srm[cl3] = a + brm[col];
                else         sh[cl3]  = tanh_fast(a + brr[col]);
            }
            __syncthreads();
        } else {
            // fused k_final: g[j-slice] = r@W_rg + qh@W_qg + brg + bqg
            const __bf16* wp2 = (m ? wqgT : wrgT) + ((size_t)(j * 64 + cl)) * DIMD + q * 128;
            const float* sv = (m ? sqh4 : sr4) + q * SR_STR;
            float a0 = 0.f, a1 = 0.f;
#pragma unroll
            for (int u = 0; u < 16; u += 2) {
                bf16x8 w0 = *(const bf16x8*)(wp2 + u * 8);
                bf16x8 w1 = *(const bf16x8*)(wp2 + u * 8 + 8);
#pragma unroll
                for (int e = 0; e < 8; e++) {
                    a0 = fmaf(sv[u * 8 + e],     (float)w0[e], a0);
                    a1 = fmaf(sv[u * 8 + 8 + e], (float)w1[e], a1);
                }
            }
            smv[tid] = a0 + a1;
            __syncthreads();
            if (tid < 64) {
                int col = j * 64 + tid;
                float a = brg[col] + bqg[col];
#pragma unroll
                for (int m2 = 0; m2 < 2; m2++)
#pragma unroll
                    for (int q2 = 0; q2 < 4; q2++)
                        a += smv[m2 * 256 + tid * 4 + q2];
                out[(size_t)b * DIMD + col] = a;
            }
        }
    }
}

// ---------------- host ----------------

extern "C" void kernel_launch(void* const* d_in, const int* in_sizes, int n_in,
                              void* d_out, int out_size, void* d_ws, size_t ws_size,
                              hipStream_t stream) {
    const float* ctx_in = (const float*)d_in[0];
    const float* q_in   = (const float*)d_in[1];
    const float* qh     = (const float*)d_in[2];
    const float* img    = (const float*)d_in[3];
    const float* W_fc1  = (const float*)d_in[4];
    const float* b_fc1  = (const float*)d_in[5];
    const float* W_fc2  = (const float*)d_in[6];
    const float* b_fc2  = (const float*)d_in[7];
    const float* W_dm   = (const float*)d_in[8];
    const float* b_dm   = (const float*)d_in[9];
    const float* W_rm   = (const float*)d_in[10];
    const float* b_rm   = (const float*)d_in[11];
    const float* W_qm   = (const float*)d_in[12];
    const float* b_qm   = (const float*)d_in[13];
    const float* W_rr   = (const float*)d_in[14];
    const float* b_rr   = (const float*)d_in[15];
    const float* W_rg   = (const float*)d_in[16];
    const float* b_rg   = (const float*)d_in[17];
    const float* W_qg   = (const float*)d_in[18];
    const float* b_qg   = (const float*)d_in[19];
    const float* W_ms   = (const float*)d_in[20];
    // d_in[21] = b_ms: unused (softmax shift-invariant)

    // workspace layout. RULE: x-region aliases acat -> only WRITTEN after g1
    // consumed acat (round-8 NaN was a violation).
    char* w = (char*)d_ws;
    __bf16* acat  = (__bf16*)w;  w += (size_t)8192 * 1024 * 2;   // 16.78 MB, dead after g1
    __bf16* qp    = (__bf16*)w;  w += (size_t)1024 * 512 * 2;
    __bf16* wcatT = (__bf16*)w;  w += (size_t)512 * 1024 * 2;
    __bf16* wdmT  = (__bf16*)w;  w += (size_t)512 * 512 * 2;
    __bf16* wqmT  = (__bf16*)w;  w += (size_t)512 * 512 * 2;
    __bf16* wrmT  = (__bf16*)w;  w += (size_t)512 * 512 * 2;
    __bf16* wrrT  = (__bf16*)w;  w += (size_t)512 * 512 * 2;
    __bf16* wrgT  = (__bf16*)w;  w += (size_t)512 * 512 * 2;
    __bf16* wqgT  = (__bf16*)w;  w += (size_t)512 * 512 * 2;
    __bf16* ctxb  = (__bf16*)w;  w += (size_t)8192 * 512 * 2;
    __bf16* ctxdm = (__bf16*)w;  w += (size_t)8192 * 512 * 2;
    // sub-allocate dead acat region (written only after g1 consumed it)
    char* x = (char*)acat;
    float*  qmf   = (float*)x;   x += (size_t)1024 * 512 * 4;      // 2.10 MB
    u64*    rpub  = (u64*)x;     x += (size_t)NB * DIMD * 8;       // 128 KB tagged
    u64*    parts = (u64*)x;     x += (size_t)NB * 8 * NS * 8;     // 512 KB tagged

    // 1. fused prep: acat + qp + all eight weight transposes
    k_prep_all<<<12288, 256, 0, stream>>>(ctx_in, img, q_in, W_fc1, W_fc2, W_dm,
                                          W_qm, W_rm, W_rr, W_rg, W_qg, acat, qp,
                                          wcatT, wdmT, wqmT, wrmT, wrrT, wrgT, wqgT);
    // 2. g1: ctx = acat @ W_cat^T + bfc1 + bfc2  (128x64 tiles, 512 blocks = 2/CU)
    k_gemm<<<dim3(64, 8), 256, 0, stream>>>(acat, wcatT, b_fc1, b_fc2, ctxb, 8192, 512, 1024, 0);
    // 3. fused post-g1: g2 + qm GEMMs only (ctxT transpose now in-scan)
    k_fused<<<576, 256, 0, stream>>>(ctxb, wdmT, b_dm, ctxdm, qp, wqmT, b_qm, qmf);
    // 4. scan + fused final: 256 blocks (8 per batch) x 512 threads, tagged sync
    k_scan<<<256, 512, 0, stream>>>(ctxdm, ctxb, wrmT, wrrT, qmf, W_ms,
                                    b_rm, b_rr, qh, wrgT, wqgT, b_rg, b_qg,
                                    parts, rpub, (float*)d_out);
}